// Round 4
// baseline (1260.695 us; speedup 1.0000x reference)
//
#include <hip/hip_runtime.h>

// ---------------------------------------------------------------------------
// EquivariantConvExp: z -> tanh(conv_exp(z, k_i)) for i = 3,2,1,0
// conv_exp = sum_{n=0..10} K^n z / n!   (7x7 'same' cross-correlation, C=1)
// log_det  = -(H*W) * sum_i k_i[center]
//
// R4 = R3 + two targeted fixes:
//  (1) inline-asm v_dot2_f32_f16 (R3 counters imply the fdot2 builtin fell
//      back to 2x v_fma_mix -> 2x VALU issue on the critical stage waves)
//  (2) lgkmcnt-only barrier (s_waitcnt lgkmcnt(0) + s_barrier) so the util
//      wave's global z-row prefetch stays in flight across barriers
//      (__syncthreads drains vmcnt(0) every step -> exposed load latency).
// Structure unchanged: 11 waves/block, waves 0..9 = series stages (lag 4
// rows/stage, 7-row register window, 1 new LDS row read/step), wave 10 =
// loader + acc init + tanh finalize + store. One barrier per step.
// ---------------------------------------------------------------------------

typedef _Float16 h2 __attribute__((ext_vector_type(2)));

#define HH 256
#define WW 256
#define NT 10                      // series terms
#define NRINGS 10                  // interfaces I_0..I_9
#define PITCH 264                  // u16 per ring row: 4 margin + 256 + 4 margin
#define RING_ELEMS (PITCH * 7)
#define ACCE (NRINGS * RING_ELEMS) // 18480 u16
#define ACC_ROWS 42
#define SMEM_U16 (ACCE + ACC_ROWS * WW) // 29232 u16 = 58464 B
#define FIN_LAG 41                 // 4*NT + 1
#define T_STEPS 301                // 43*7 >= 297 needed steps
#define NTHREADS 704
#define PF 3                       // global-load prefetch depth (steps)

union U32H2 { unsigned int u; h2 h; };
static __device__ __forceinline__ h2 uh(unsigned int u) { U32H2 x; x.u = u; return x.h; }
static __device__ __forceinline__ unsigned int hu(h2 h) { U32H2 x; x.h = h; return x.u; }
static __device__ __forceinline__ unsigned int pk2f(float lo, float hi) {
    h2 h; h[0] = (_Float16)lo; h[1] = (_Float16)hi; return hu(h);
}

// acc += dot2(a.f16x2, b.f16x2) with fp32 accumulate — forced single instr.
#define DOT2(acc, a, b) \
    asm("v_dot2_f32_f16 %0, %1, %2, %0" : "+v"(acc) : "v"(a), "v"(b))

// lgkm-only workgroup barrier: LDS producer->consumer ordering without
// draining vmcnt (keeps global prefetch loads in flight across steps).
static __device__ __forceinline__ void barrier_lgkm() {
    asm volatile("s_waitcnt lgkmcnt(0)" ::: "memory");
    __builtin_amdgcn_s_barrier();
    asm volatile("" ::: "memory");
}

static __device__ __forceinline__ float tanh_fast(float x) {
    float e = __expf(2.0f * x);
    return 1.0f - 2.0f / (e + 1.0f);   // inf-safe
}

// Packed per-row kernel taps (8 u32 per ky):
//  [0]=(0,w0) [1]=(w1,w2) [2]=(w3,w4) [3]=(w5,w6)   (even output cols)
//  [4]=(w0,w1) [5]=(w2,w3) [6]=(w4,w5) [7]=(w6,0)   (odd  output cols)
__global__ void prep_kernel(const float* __restrict__ filters,
                            float* __restrict__ logdet,
                            unsigned int* __restrict__ pk) {
    const int tid = threadIdx.x;
    if (tid < 28) {
        const int blk = tid / 7, ky = tid - blk * 7;
        const float* w = filters + blk * 49 + ky * 7;
        unsigned int* o = pk + blk * 64 + ky * 8;
        o[0] = pk2f(0.f, w[0]);  o[1] = pk2f(w[1], w[2]);
        o[2] = pk2f(w[3], w[4]); o[3] = pk2f(w[5], w[6]);
        o[4] = pk2f(w[0], w[1]); o[5] = pk2f(w[2], w[3]);
        o[6] = pk2f(w[4], w[5]); o[7] = pk2f(w[6], 0.f);
    }
    const float c = -(float)(HH * WW) *
        (filters[24] + filters[49 + 24] + filters[98 + 24] + filters[147 + 24]);
    for (int j = tid; j < 256; j += blockDim.x) logdet[j] = c;
}

template <int IN_F16, int OUT_F16>
__global__ __launch_bounds__(NTHREADS)
void cascade_kernel(const void* __restrict__ in_, void* __restrict__ out_,
                    const unsigned int* __restrict__ pkg) {
    __shared__ __align__(16) unsigned short smem[SMEM_U16];
    const int tid = threadIdx.x;
    const int wav = tid >> 6;
    const int lane = tid & 63;
    const int img = blockIdx.x;

    { // zero LDS (margins + initial ring/acc state must be 0)
        unsigned int* s4 = (unsigned int*)smem;
        for (int i = tid; i < SMEM_U16 / 2; i += NTHREADS) s4[i] = 0u;
    }

    unsigned int Kc[56];
#pragma unroll
    for (int i = 0; i < 56; ++i)
        Kc[i] = __builtin_amdgcn_readfirstlane(pkg[i]);

    const bool is_stage = (wav < NT);
    const bool is_util = (wav == NT);
    const int stg = wav + 1;                 // 1..10 for stage waves
    const float sinv = 1.0f / (float)stg;
    const int rb_in = wav * RING_ELEMS;      // input ring I_{stg-1}
    const int rb_out = (wav + 1) * RING_ELEMS; // output ring I_stg (stg<NT only)

    // Precomputed per-unroll-slot LDS indices (u16 units). t0 % 7 == 0 always,
    // so ring slot depends only on u (compile-time) + per-wave constant.
    int rdIdx[7], wrIdx[7];
#pragma unroll
    for (int u = 0; u < 7; ++u) {
        const int sR = (((u + 3 - 4 * stg) % 7) + 7) % 7;  // slot of row q+3
        const int sW = (((u - 4 * stg) % 7) + 7) % 7;      // slot of row q
        rdIdx[u] = rb_in + sR * PITCH + 4 * lane;          // halo read (payload-4)
        wrIdx[u] = rb_out + sW * PITCH + 4 + 4 * lane;     // payload write
    }

    // 7-row register window; age j at unroll-step u lives in slot (u+j)%7.
    // Zero-init => rows < 0 read as zero (priming).
    unsigned int win[7][6];
#pragma unroll
    for (int a = 0; a < 7; ++a)
#pragma unroll
        for (int b = 0; b < 6; ++b) win[a][b] = 0u;

    // Incremental wrapping acc-row pointers (row = (t - X) mod 42 at step t).
    const int ACC_END = ACCE + ACC_ROWS * WW;
    int accS = ACCE + ((((-4 * stg) % ACC_ROWS) + ACC_ROWS) % ACC_ROWS) * WW + 4 * lane;
    int accI = ACCE + 4 * lane;              // util z-init row t
    int accF = ACCE + 1 * WW + 4 * lane;     // util finalize row t-41

    const unsigned short* gin16 = (const unsigned short*)in_ + (size_t)img * (HH * WW);
    const float* gin32 = (const float*)in_ + (size_t)img * (HH * WW);
    unsigned short* gout16 = (unsigned short*)out_ + (size_t)img * (HH * WW);
    float* gout32 = (float*)out_ + (size_t)img * (HH * WW);

    // z-row prefetch registers (row r sits in slot r%7; loaded PF steps early)
    uint2 zh[7]; float4 zf[7];
    if (is_util) {
#pragma unroll
        for (int r = 0; r < PF; ++r) {
            if (IN_F16) zh[r] = *(const uint2*)(gin16 + r * WW + 4 * lane);
            else        zf[r] = *(const float4*)(gin32 + r * WW + 4 * lane);
        }
    }
    barrier_lgkm();

    for (int t0 = 0; t0 < T_STEPS; t0 += 7) {
#pragma unroll
        for (int u = 0; u < 7; ++u) {
            const int t = t0 + u;
            if (is_stage) {
                const int q = t - 4 * stg;         // output row of this stage
                { // pull the newly-available row (q+3) into window age-6 slot
                    const uint2* p = (const uint2*)&smem[rdIdx[u]];
                    const uint2 A = p[0], B = p[1], C = p[2];
                    win[(u + 6) % 7][0] = A.x; win[(u + 6) % 7][1] = A.y;
                    win[(u + 6) % 7][2] = B.x; win[(u + 6) % 7][3] = B.y;
                    win[(u + 6) % 7][4] = C.x; win[(u + 6) % 7][5] = C.y;
                }
                if (q >= 0 && q < HH) {
                    float o0 = 0.f, o1 = 0.f, o2 = 0.f, o3 = 0.f;
#pragma unroll
                    for (int ky = 0; ky < 7; ++ky) {
                        const unsigned int v0 = win[(u + ky) % 7][0], v1 = win[(u + ky) % 7][1],
                                           v2 = win[(u + ky) % 7][2], v3 = win[(u + ky) % 7][3],
                                           v4 = win[(u + ky) % 7][4], v5 = win[(u + ky) % 7][5];
                        const unsigned int P0 = Kc[ky * 8 + 0], P1 = Kc[ky * 8 + 1],
                                           P2 = Kc[ky * 8 + 2], P3 = Kc[ky * 8 + 3],
                                           P4 = Kc[ky * 8 + 4], P5 = Kc[ky * 8 + 5],
                                           P6 = Kc[ky * 8 + 6], P7 = Kc[ky * 8 + 7];
                        DOT2(o0, v0, P0); DOT2(o0, v1, P1);
                        DOT2(o0, v2, P2); DOT2(o0, v3, P3);
                        DOT2(o1, v1, P4); DOT2(o1, v2, P5);
                        DOT2(o1, v3, P6); DOT2(o1, v4, P7);
                        DOT2(o2, v1, P0); DOT2(o2, v2, P1);
                        DOT2(o2, v3, P2); DOT2(o2, v4, P3);
                        DOT2(o3, v2, P4); DOT2(o3, v3, P5);
                        DOT2(o3, v4, P6); DOT2(o3, v5, P7);
                    }
                    o0 *= sinv; o1 *= sinv; o2 *= sinv; o3 *= sinv;
                    uint2 w; w.x = pk2f(o0, o1); w.y = pk2f(o2, o3);
                    if (stg < NT) *(uint2*)&smem[wrIdx[u]] = w;   // hand-off row q
                    // acc[q] += prod (f16 packed RMW; only this wave touches row q this step)
                    const uint2 av = *(const uint2*)&smem[accS];
                    const h2 lo = uh(av.x) + uh(w.x), hi = uh(av.y) + uh(w.y);
                    uint2 nv; nv.x = hu(lo); nv.y = hu(hi);
                    *(uint2*)&smem[accS] = nv;
                } else if (q >= HH && q <= HH + 2 && stg < NT) {
                    // bottom boundary rows must read as zero downstream
                    uint2 w; w.x = 0u; w.y = 0u;
                    *(uint2*)&smem[wrIdx[u]] = w;
                }
                accS += WW; if (accS >= ACC_END) accS -= ACC_ROWS * WW;
            } else if (is_util) {
                // issue global load for row t+PF (consumed PF steps later;
                // stays in flight across lgkm-only barriers)
                if (t + PF < HH) {
                    if (IN_F16) zh[(u + PF) % 7] = *(const uint2*)(gin16 + (size_t)(t + PF) * WW + 4 * lane);
                    else        zf[(u + PF) % 7] = *(const float4*)(gin32 + (size_t)(t + PF) * WW + 4 * lane);
                }
                // write row t (z) to ring0 + acc init; zeros for boundary rows
                if (t <= HH + 2) {
                    uint2 w;
                    if (t < HH) {
                        if (IN_F16) w = zh[u];
                        else { const float4 g = zf[u]; w.x = pk2f(g.x, g.y); w.y = pk2f(g.z, g.w); }
                    } else { w.x = 0u; w.y = 0u; }
                    *(uint2*)&smem[u * PITCH + 4 + 4 * lane] = w;  // ring0 slot t%7 == u
                    if (t < HH) *(uint2*)&smem[accI] = w;          // acc init = z
                }
                // finalize row f = t - 41: tanh + store
                const int f = t - FIN_LAG;
                if (f >= 0 && f < HH) {
                    const uint2 av = *(const uint2*)&smem[accF];
                    const h2 a = uh(av.x), b = uh(av.y);
                    const float r0 = tanh_fast((float)a[0]), r1 = tanh_fast((float)a[1]);
                    const float r2 = tanh_fast((float)b[0]), r3 = tanh_fast((float)b[1]);
                    if (OUT_F16) {
                        uint2 w; w.x = pk2f(r0, r1); w.y = pk2f(r2, r3);
                        *(uint2*)(gout16 + (size_t)f * WW + 4 * lane) = w;
                    } else {
                        float4 w; w.x = r0; w.y = r1; w.z = r2; w.w = r3;
                        *(float4*)(gout32 + (size_t)f * WW + 4 * lane) = w;
                    }
                }
                accI += WW; if (accI >= ACC_END) accI -= ACC_ROWS * WW;
                accF += WW; if (accF >= ACC_END) accF -= ACC_ROWS * WW;
            }
            // Single barrier: within a step every wave touches distinct LDS
            // rows/slots; producer->consumer hand-off crosses exactly one barrier.
            barrier_lgkm();
        }
    }
}

extern "C" void kernel_launch(void* const* d_in, const int* in_sizes, int n_in,
                              void* d_out, int out_size, void* d_ws, size_t ws_size,
                              hipStream_t stream) {
    (void)in_sizes; (void)n_in; (void)out_size; (void)ws_size;
    const float* x = (const float*)d_in[0];
    const float* fl = (const float*)d_in[1];
    float* out = (float*)d_out;
    float* logdet = out + (size_t)256 * 256 * 256;

    // f16 ping buffers: A in workspace, B aliases d_out's z region (safe: z is
    // written fp32 only by the final block, after B has been consumed).
    unsigned short* bufA = (unsigned short*)d_ws;
    unsigned short* bufB = (unsigned short*)d_out;
    unsigned int* pk = (unsigned int*)((char*)d_ws + (size_t)256 * 256 * 256 * 2);

    prep_kernel<<<1, 64, 0, stream>>>(fl, logdet, pk);
    // blocks applied in reversed order: filters[3], [2], [1], [0]
    cascade_kernel<0, 1><<<256, NTHREADS, 0, stream>>>(x,    bufA, pk + 3 * 64);
    cascade_kernel<1, 1><<<256, NTHREADS, 0, stream>>>(bufA, bufB, pk + 2 * 64);
    cascade_kernel<1, 1><<<256, NTHREADS, 0, stream>>>(bufB, bufA, pk + 1 * 64);
    cascade_kernel<1, 0><<<256, NTHREADS, 0, stream>>>(bufA, out,  pk + 0 * 64);
}

// Round 5
// 996.823 us; speedup vs baseline: 1.2647x; 1.2647x over previous
//
#include <hip/hip_runtime.h>

// ---------------------------------------------------------------------------
// EquivariantConvExp: z -> tanh(conv_exp(z, k_i)) for i = 3,2,1,0
// conv_exp = sum_{n=0..10} K^n z / n!   (7x7 'same' cross-correlation, C=1)
// log_det  = -(H*W) * sum_i k_i[center]
//
// R5: MFMA line-buffer cascade. Same schedule as R3 (11 waves: 10 series
// stages lag-4-rows apart + 1 util wave; 1 output row/stage/step; one
// __syncthreads per step), but the conv math runs on the matrix pipe:
//   D[seg][n] (16 segs x 16 cols = one 256-wide row) =
//     sum_ky mfma_f32_16x16x32_f16( A_row(q+ky-3), B_ky, D )
// A-frag: lane holds 8 contiguous f16 of the padded row at
//   col 16*(lane&15) - 8 + 8*(lane>>4) + e   (one ds_read_b128, kept in a
//   7-deep register ring: 1 new row read per step).
// B-frag: banded Toeplitz, lane holds W[k=8*(lane>>4)+e][n=lane&15] =
//   w_ky[k-n-5] (0 outside band), prebuilt in prep_kernel, scaled by 1/stage.
// K-enumeration cancels (A,B built with the same (g,e) enumeration);
// D layout (row=(lane>>4)*4+reg from 1st operand, col=lane&15 from 2nd) is
// the HW-verified mapping.
// ---------------------------------------------------------------------------

typedef _Float16 h2 __attribute__((ext_vector_type(2)));
typedef _Float16 f16x8 __attribute__((ext_vector_type(8)));
typedef float f32x4 __attribute__((ext_vector_type(4)));

#define HH 256
#define WW 256
#define NT 10                      // series terms
#define NRINGS 10                  // interfaces I_0..I_9
#define PITCH 272                  // f16 per ring row: 8 margin + 256 + 8 margin
#define RING_ELEMS (PITCH * 7)     // 1904
#define ACCE (NRINGS * RING_ELEMS) // 19040 u16
#define ACC_ROWS 42
#define SMEM_U16 (ACCE + ACC_ROWS * WW) // 29792 u16 = 59584 B
#define FIN_LAG 41                 // 4*NT + 1
#define T_STEPS 301                // 43*7 >= 297 needed steps
#define NTHREADS 704
#define PF 3                       // global-load prefetch depth (steps)

union U32H2 { unsigned int u; h2 h; };
union U4F8 { uint4 u; f16x8 h; };
union USH { unsigned short u; _Float16 h; };

static __device__ __forceinline__ h2 uh(unsigned int u) { U32H2 x; x.u = u; return x.h; }
static __device__ __forceinline__ unsigned int hu(h2 h) { U32H2 x; x.h = h; return x.u; }
static __device__ __forceinline__ unsigned int pk2f(float lo, float hi) {
    h2 h; h[0] = (_Float16)lo; h[1] = (_Float16)hi; return hu(h);
}

static __device__ __forceinline__ float tanh_fast(float x) {
    float e = __expf(2.0f * x);
    return 1.0f - 2.0f / (e + 1.0f);   // inf-safe
}

// prep: logdet + per-lane MFMA B-fragment tables.
// pkB layout: [blk(4)][ky(7)][lane(64)][e(8)] f16, one uint4 per (blk,ky,lane).
__global__ void prep_kernel(const float* __restrict__ filters,
                            float* __restrict__ logdet,
                            unsigned short* __restrict__ pkB) {
    const int tid = threadIdx.x;               // 256 threads
    for (int i = tid; i < 4 * 7 * 64; i += 256) {
        const int blk = i / 448, r = i - blk * 448, ky = r >> 6, lane = r & 63;
        const float* w = filters + blk * 49 + ky * 7;
        const int g = lane >> 4, n = lane & 15;
        unsigned short* o = pkB + (size_t)i * 8;
        for (int e = 0; e < 8; ++e) {
            const int tap = 8 * g + e - n - 5;  // W[k][n] = w[k-n-5], band 0..6
            const float v = (tap >= 0 && tap < 7) ? w[tap] : 0.f;
            USH c; c.h = (_Float16)v;
            o[e] = c.u;
        }
    }
    const float c = -(float)(HH * WW) *
        (filters[24] + filters[49 + 24] + filters[98 + 24] + filters[147 + 24]);
    for (int j = tid; j < 256; j += blockDim.x) logdet[j] = c;
}

template <int IN_F16, int OUT_F16>
__global__ __launch_bounds__(NTHREADS)
void cascade_kernel(const void* __restrict__ in_, void* __restrict__ out_,
                    const uint4* __restrict__ pkBg) {
    __shared__ __align__(16) unsigned short smem[SMEM_U16];
    const int tid = threadIdx.x;
    const int wav = tid >> 6;
    const int lane = tid & 63;
    const int img = blockIdx.x;
    const int g = lane >> 4, n = lane & 15;

    { // zero LDS (margins + initial ring/acc state must be 0)
        unsigned int* s4 = (unsigned int*)smem;
        for (int i = tid; i < SMEM_U16 / 2; i += NTHREADS) s4[i] = 0u;
    }

    const bool is_stage = (wav < NT);
    const bool is_util = (wav == NT);
    const int stg = wav + 1;                   // 1..10 for stage waves
    const int rb_in = wav * RING_ELEMS;        // input ring I_{stg-1}
    const int rb_out = (wav + 1) * RING_ELEMS; // output ring I_stg (stg<NT only)

    // B fragments (Toeplitz / stage), scaled by 1/stg in f16
    f16x8 B[7];
    if (is_stage) {
        const _Float16 sh = (_Float16)(1.0f / (float)stg);
        f16x8 sv;
#pragma unroll
        for (int j = 0; j < 8; ++j) sv[j] = sh;
#pragma unroll
        for (int ky = 0; ky < 7; ++ky) {
            U4F8 raw; raw.u = pkBg[ky * 64 + lane];
            B[ky] = raw.h * sv;
        }
    }

    // Per-unroll-slot LDS indices (f16 units). t0 % 7 == 0 always.
    int rdIdx[7], wrIdx[7];
#pragma unroll
    for (int u = 0; u < 7; ++u) {
        const int sR = (((u + 3 - 4 * stg) % 7) + 7) % 7;  // slot of row q+3
        const int sW = (((u - 4 * stg) % 7) + 7) % 7;      // slot of row q
        // A-frag read: col 16n-8+8g  ->  f16 idx (margin 8 included) 16n+8g
        rdIdx[u] = rb_in + sR * PITCH + 16 * n + 8 * g;
        // D writes: image col 64g+16r+n -> f16 idx 8+64g+n (+16r per reg)
        wrIdx[u] = rb_out + sW * PITCH + 8 + 64 * g + n;
    }
    const int accCol = 64 * g + n;             // acc has no margins

    // 7-row A-fragment register ring; zero-init => rows < 0 read as zero.
    f16x8 win[7];
#pragma unroll
    for (int a = 0; a < 7; ++a)
#pragma unroll
        for (int b = 0; b < 8; ++b) win[a][b] = (_Float16)0.f;

    // Wrapping acc-row pointers (row = (t - X) mod 42 at step t).
    const int ACC_END = ACCE + ACC_ROWS * WW;
    int accS = ACCE + ((((-4 * stg) % ACC_ROWS) + ACC_ROWS) % ACC_ROWS) * WW + accCol;
    int accI = ACCE + 4 * lane;                // util z-init row t
    int accF = ACCE + 1 * WW + 4 * lane;       // util finalize row t-41

    const unsigned short* gin16 = (const unsigned short*)in_ + (size_t)img * (HH * WW);
    const float* gin32 = (const float*)in_ + (size_t)img * (HH * WW);
    unsigned short* gout16 = (unsigned short*)out_ + (size_t)img * (HH * WW);
    float* gout32 = (float*)out_ + (size_t)img * (HH * WW);

    // z-row prefetch registers (row r sits in slot r%7; loaded PF steps early)
    uint2 zh[7]; float4 zf[7];
    if (is_util) {
#pragma unroll
        for (int r = 0; r < PF; ++r) {
            if (IN_F16) zh[r] = *(const uint2*)(gin16 + r * WW + 4 * lane);
            else        zf[r] = *(const float4*)(gin32 + r * WW + 4 * lane);
        }
    }
    __syncthreads();

    for (int t0 = 0; t0 < T_STEPS; t0 += 7) {
#pragma unroll
        for (int u = 0; u < 7; ++u) {
            const int t = t0 + u;
            if (is_stage) {
                const int q = t - 4 * stg;     // output row of this stage
                // pull the newly-available row (q+3) into the age-6 ring slot
                win[(u + 6) % 7] = *(const f16x8*)&smem[rdIdx[u]];
                if (q >= 0 && q < HH) {
                    f32x4 D = {0.f, 0.f, 0.f, 0.f};
#pragma unroll
                    for (int ky = 0; ky < 7; ++ky)
                        D = __builtin_amdgcn_mfma_f32_16x16x32_f16(
                                win[(u + ky) % 7], B[ky], D, 0, 0, 0);
                    // epilogue: f16 convert, ring hand-off, acc RMW
#pragma unroll
                    for (int r = 0; r < 3 + 1; ++r) {
                        const _Float16 hv = (_Float16)D[r];
                        if (stg < NT) *(_Float16*)&smem[wrIdx[u] + 16 * r] = hv;
                        _Float16* ap = (_Float16*)&smem[accS + 16 * r];
                        *ap = *ap + hv;
                    }
                } else if (q >= HH && q <= HH + 2 && stg < NT) {
                    // bottom boundary rows must read as zero downstream
#pragma unroll
                    for (int r = 0; r < 4; ++r)
                        *(_Float16*)&smem[wrIdx[u] + 16 * r] = (_Float16)0.f;
                }
                accS += WW; if (accS >= ACC_END) accS -= ACC_ROWS * WW;
            } else if (is_util) {
                // issue global load for row t+PF (consumed PF steps later)
                if (t + PF < HH) {
                    if (IN_F16) zh[(u + PF) % 7] = *(const uint2*)(gin16 + (size_t)(t + PF) * WW + 4 * lane);
                    else        zf[(u + PF) % 7] = *(const float4*)(gin32 + (size_t)(t + PF) * WW + 4 * lane);
                }
                // write row t (z) to ring0 + acc init; zeros for boundary rows
                if (t <= HH + 2) {
                    uint2 w;
                    if (t < HH) {
                        if (IN_F16) w = zh[u];
                        else { const float4 gz = zf[u]; w.x = pk2f(gz.x, gz.y); w.y = pk2f(gz.z, gz.w); }
                    } else { w.x = 0u; w.y = 0u; }
                    *(uint2*)&smem[u * PITCH + 8 + 4 * lane] = w;  // ring0 slot t%7 == u
                    if (t < HH) *(uint2*)&smem[accI] = w;          // acc init = z
                }
                // finalize row f = t - 41: tanh + store
                const int f = t - FIN_LAG;
                if (f >= 0 && f < HH) {
                    const uint2 av = *(const uint2*)&smem[accF];
                    const h2 a = uh(av.x), b = uh(av.y);
                    const float r0 = tanh_fast((float)a[0]), r1 = tanh_fast((float)a[1]);
                    const float r2 = tanh_fast((float)b[0]), r3 = tanh_fast((float)b[1]);
                    if (OUT_F16) {
                        uint2 w; w.x = pk2f(r0, r1); w.y = pk2f(r2, r3);
                        *(uint2*)(gout16 + (size_t)f * WW + 4 * lane) = w;
                    } else {
                        float4 w; w.x = r0; w.y = r1; w.z = r2; w.w = r3;
                        *(float4*)(gout32 + (size_t)f * WW + 4 * lane) = w;
                    }
                }
                accI += WW; if (accI >= ACC_END) accI -= ACC_ROWS * WW;
                accF += WW; if (accF >= ACC_END) accF -= ACC_ROWS * WW;
            }
            // Single barrier: within a step every wave touches distinct LDS
            // rows/slots; producer->consumer hand-off crosses exactly one barrier.
            __syncthreads();
        }
    }
}

extern "C" void kernel_launch(void* const* d_in, const int* in_sizes, int n_in,
                              void* d_out, int out_size, void* d_ws, size_t ws_size,
                              hipStream_t stream) {
    (void)in_sizes; (void)n_in; (void)out_size; (void)ws_size;
    const float* x = (const float*)d_in[0];
    const float* fl = (const float*)d_in[1];
    float* out = (float*)d_out;
    float* logdet = out + (size_t)256 * 256 * 256;

    // f16 ping buffers: A in workspace, B aliases d_out's z region (safe: z is
    // written fp32 only by the final block, after B has been consumed).
    unsigned short* bufA = (unsigned short*)d_ws;
    unsigned short* bufB = (unsigned short*)d_out;
    unsigned short* pkB = (unsigned short*)((char*)d_ws + (size_t)256 * 256 * 256 * 2);

    prep_kernel<<<1, 256, 0, stream>>>(fl, logdet, pkB);
    const uint4* pb = (const uint4*)pkB;       // one uint4 per (blk,ky,lane)
    // blocks applied in reversed order: filters[3], [2], [1], [0]
    cascade_kernel<0, 1><<<256, NTHREADS, 0, stream>>>(x,    bufA, pb + 3 * 448);
    cascade_kernel<1, 1><<<256, NTHREADS, 0, stream>>>(bufA, bufB, pb + 2 * 448);
    cascade_kernel<1, 1><<<256, NTHREADS, 0, stream>>>(bufB, bufA, pb + 1 * 448);
    cascade_kernel<1, 0><<<256, NTHREADS, 0, stream>>>(bufA, out,  pb + 0 * 448);
}